// Round 2
// baseline (924.187 us; speedup 1.0000x reference)
//
#include <hip/hip_runtime.h>
#include <math.h>

#define N_RN 100000
#define N_ED 1200000
#define N_G  4096
#define SCAN_CH 256
#define SCAN_NB ((N_RN + SCAN_CH - 1) / SCAN_CH)   // 391

__device__ __forceinline__ float lrelu(float x) { return x > 0.f ? x : 0.1f * x; }

// h = r_node @ W_r (wave/node, lane=col, row via coalesced LDS); fused hs/hd layer0
__global__ void k_embed_h(const float* __restrict__ r_node,
                          const float* __restrict__ W_r,
                          const float* __restrict__ a_s0,
                          const float* __restrict__ a_d0,
                          float* __restrict__ h,
                          float* __restrict__ hs, float* __restrict__ hd) {
    __shared__ float Wl[64 * 64];
    __shared__ float arow[4][64];
    int tid = threadIdx.x;
    for (int i = tid; i < 4096; i += 256) Wl[i] = W_r[i];
    __syncthreads();
    int lane = tid & 63, w = tid >> 6;
    float asj = a_s0[lane], adj = a_d0[lane];
    int wid = blockIdx.x * 4 + w;
    int nw = gridDim.x * 4;
    for (int n = wid; n < N_RN; n += nw) {
        arow[w][lane] = r_node[(size_t)n * 64 + lane];
        float acc = 0.f;
#pragma unroll
        for (int d4 = 0; d4 < 16; ++d4) {
            float4 a = *(const float4*)&arow[w][d4 * 4];
            int d = d4 * 4;
            acc += a.x * Wl[(d + 0) * 64 + lane];
            acc += a.y * Wl[(d + 1) * 64 + lane];
            acc += a.z * Wl[(d + 2) * 64 + lane];
            acc += a.w * Wl[(d + 3) * 64 + lane];
        }
        h[(size_t)n * 64 + lane] = acc;
        float x = acc * asj, y = acc * adj;
#pragma unroll
        for (int off = 32; off; off >>= 1) {
            x += __shfl_xor(x, off, 64);
            y += __shfl_xor(y, off, 64);
        }
        if (lane == 0) { hs[n] = x; hd[n] = y; }
    }
}

// streaming per-layer GEMM: hWm = h @ Wm[l]  (wave/node, same verified pattern)
__global__ void k_hwm(const float* __restrict__ h,
                      const float* __restrict__ Wm_l,
                      float* __restrict__ hWm) {
    __shared__ float Wl[64 * 64];
    __shared__ float arow[4][64];
    int tid = threadIdx.x;
    for (int i = tid; i < 4096; i += 256) Wl[i] = Wm_l[i];
    __syncthreads();
    int lane = tid & 63, w = tid >> 6;
    int wid = blockIdx.x * 4 + w;
    int nw = gridDim.x * 4;
    for (int n = wid; n < N_RN; n += nw) {
        arow[w][lane] = h[(size_t)n * 64 + lane];
        float acc = 0.f;
#pragma unroll
        for (int d4 = 0; d4 < 16; ++d4) {
            float4 a = *(const float4*)&arow[w][d4 * 4];
            int d = d4 * 4;
            acc += a.x * Wl[(d + 0) * 64 + lane];
            acc += a.y * Wl[(d + 1) * 64 + lane];
            acc += a.z * Wl[(d + 2) * 64 + lane];
            acc += a.w * Wl[(d + 3) * 64 + lane];
        }
        hWm[(size_t)n * 64 + lane] = acc;
    }
}

// WeWm[l] = W_e @ Wm[l]  (16x64 per layer); also was_all[l][t] = W_e[t,:] . a_e[l]
__global__ void k_wewm(const float* __restrict__ W_e,
                       const float* __restrict__ Wm,
                       const float* __restrict__ a_e,
                       float* __restrict__ WeWm,
                       float* __restrict__ was_all) {
    int idx = blockIdx.x * blockDim.x + threadIdx.x;   // 17*256
    if (idx < 4096) {
        int l = idx >> 10, rem = idx & 1023;
        int t = rem >> 6, j = rem & 63;
        float acc = 0.f;
        for (int d = 0; d < 64; ++d)
            acc += W_e[t * 64 + d] * Wm[l * 4096 + d * 64 + j];
        WeWm[idx] = acc;
    } else {
        int r = idx - 4096;
        if (r < 64) {
            int l = r >> 4, t = r & 15;
            float acc = 0.f;
            for (int j = 0; j < 64; ++j)
                acc += W_e[t * 64 + j] * a_e[l * 64 + j];
            was_all[r] = acc;
        }
    }
}

// ---- CSR build ----
__global__ void k_hist(const int* __restrict__ dst, int* __restrict__ deg) {
    int k = blockIdx.x * blockDim.x + threadIdx.x;
    if (k < N_ED) atomicAdd(deg + dst[k], 1);
}

__global__ void k_scan_a(const int* __restrict__ deg, int* __restrict__ bsum) {
    __shared__ int lds[SCAN_CH];
    int b = blockIdx.x, t = threadIdx.x;
    int i = b * SCAN_CH + t;
    int v = (i < N_RN) ? deg[i] : 0;
    lds[t] = v;
    __syncthreads();
    for (int d = 128; d; d >>= 1) {
        if (t < d) lds[t] += lds[t + d];
        __syncthreads();
    }
    if (t == 0) bsum[b] = lds[0];
}

__global__ void k_scan_b(int* __restrict__ bsum) {
    __shared__ int lds[512];
    int t = threadIdx.x;
    int v = (t < SCAN_NB) ? bsum[t] : 0;
    lds[t] = v;
    __syncthreads();
    for (int d = 1; d < 512; d <<= 1) {
        int u = (t >= d) ? lds[t - d] : 0;
        __syncthreads();
        lds[t] += u;
        __syncthreads();
    }
    if (t < SCAN_NB) bsum[t] = lds[t] - v;  // exclusive
}

__global__ void k_scan_c(const int* __restrict__ deg, const int* __restrict__ bsum,
                         int* __restrict__ off, int* __restrict__ cur) {
    __shared__ int lds[SCAN_CH];
    int b = blockIdx.x, t = threadIdx.x;
    int i = b * SCAN_CH + t;
    int v = (i < N_RN) ? deg[i] : 0;
    lds[t] = v;
    __syncthreads();
    for (int d = 1; d < SCAN_CH; d <<= 1) {
        int u = (t >= d) ? lds[t - d] : 0;
        __syncthreads();
        lds[t] += u;
        __syncthreads();
    }
    if (i < N_RN) {
        int incl = bsum[b] + lds[t];
        off[i + 1] = incl;
        cur[i] = incl - v;
        if (i == 0) off[0] = 0;
    }
}

// scatter edges into dst-sorted order: src_perm + raw 16-float edge row (r16_perm)
__global__ void k_scatter(const float* __restrict__ r_edge,
                          const int* __restrict__ src, const int* __restrict__ dst,
                          int* __restrict__ cur,
                          int* __restrict__ src_perm,
                          float* __restrict__ r16_perm) {
    int k = blockIdx.x * blockDim.x + threadIdx.x;
    if (k >= N_ED) return;
    const float4* row = (const float4*)(r_edge + (size_t)k * 16);
    float4 r0 = row[0], r1 = row[1], r2 = row[2], r3 = row[3];
    int pos = atomicAdd(cur + dst[k], 1);
    src_perm[pos] = src[k];
    float4* o = (float4*)(r16_perm + (size_t)pos * 16);
    o[0] = r0; o[1] = r1; o[2] = r2; o[3] = r3;
}

// fused per-layer conv: wave per node, two-phase schedule, gathers PRE-MULTIPLIED
// hWm rows (h@Wm hoisted to k_hwm) so there is no per-node 64x64 matvec and no
// Wm LDS stage -> ~7.3KB LDS, 8 blocks/CU residency.
__global__ void k_layer(const float* __restrict__ h_in,
                        const float* __restrict__ hWm,
                        const float* __restrict__ hs, const float* __restrict__ hd,
                        const int* __restrict__ off,
                        const int* __restrict__ src_perm,
                        const float* __restrict__ r16_perm,
                        const float* __restrict__ was_l,   // 16 floats: W_e @ a_e[l]
                        const float* __restrict__ WeWm_l,
                        const float* __restrict__ a_s_n, const float* __restrict__ a_d_n,
                        float* __restrict__ h_out,
                        float* __restrict__ hs_out, float* __restrict__ hd_out) {
    __shared__ float Ww[16 * 64];
    __shared__ float arow[4][64];
    __shared__ float rrow[4][16];
    __shared__ float wbuf[4][64];
    __shared__ int   skbuf[4][64];
    int tid = threadIdx.x;
    for (int i = tid; i < 1024; i += 256) Ww[i] = WeWm_l[i];
    __syncthreads();
    int lane = tid & 63, w = tid >> 6;
    int g = lane >> 4, lg = lane & 15;
    float asj = a_s_n[lane], adj = a_d_n[lane];
    // uniform edge-attention row (compiler: scalar loads)
    float wr[16];
#pragma unroll
    for (int t = 0; t < 16; ++t) wr[t] = was_l[t];
    int wid = blockIdx.x * 4 + w;
    int nw = gridDim.x * 4;
    for (int n = wid; n < N_RN; n += nw) {
        int base = off[n], end = off[n + 1];
        float hdn = hd[n];
        float m = -1e38f;
        float s = 0.f, racc = 0.f;
        float acc0 = 0.f, acc1 = 0.f, acc2 = 0.f, acc3 = 0.f;
        for (int cb = base; cb < end; cb += 64) {
            int cend = cb + 64 < end ? cb + 64 : end;
            int cnt = cend - cb;
            // ---- phase 1: lane-per-edge logits, in-register edge dot ----
            int pos = cb + lane;
            float lgt = -1e38f;
            int sk = 0;
            if (pos < cend) {
                sk = src_perm[pos];
                const float4* rp = (const float4*)(r16_perm + (size_t)pos * 16);
                float4 r0 = rp[0], r1 = rp[1], r2 = rp[2], r3 = rp[3];
                float ep = r0.x * wr[0] + r0.y * wr[1] + r0.z * wr[2] + r0.w * wr[3]
                         + r1.x * wr[4] + r1.y * wr[5] + r1.z * wr[6] + r1.w * wr[7]
                         + r2.x * wr[8] + r2.y * wr[9] + r2.z * wr[10] + r2.w * wr[11]
                         + r3.x * wr[12] + r3.y * wr[13] + r3.z * wr[14] + r3.w * wr[15];
                lgt = lrelu(hs[sk] + hdn + ep);
            }
            float cm = lgt;
#pragma unroll
            for (int o = 32; o; o >>= 1) cm = fmaxf(cm, __shfl_xor(cm, o, 64));
            float newm = fmaxf(m, cm);
            float scale = (m > -1e37f) ? __expf(m - newm) : 0.f;
            s *= scale; racc *= scale;
            acc0 *= scale; acc1 *= scale; acc2 *= scale; acc3 *= scale;
            m = newm;
            float wv = (pos < cend) ? __expf(lgt - m) : 0.f;
            s += wv;                      // per-lane; full reduce at node end
            wbuf[w][lane] = wv;
            skbuf[w][lane] = sk;
            // ---- phase 2: 4 groups x 16 lanes, gather hWm rows, no shuffles ----
            for (int c = 0; c < cnt; c += 4) {
                int e = c + g;
                if (e < cnt) {
                    float wgt = wbuf[w][e];
                    int sk2 = skbuf[w][e];
                    const float4 hv = *(const float4*)(hWm + (size_t)sk2 * 64 + (lg << 2));
                    acc0 += wgt * hv.x; acc1 += wgt * hv.y;
                    acc2 += wgt * hv.z; acc3 += wgt * hv.w;
                    racc += wgt * r16_perm[(size_t)(cb + e) * 16 + lg];
                }
            }
        }
        // reduce across groups (acc/racc) and full wave (s)
        acc0 += __shfl_xor(acc0, 16, 64); acc0 += __shfl_xor(acc0, 32, 64);
        acc1 += __shfl_xor(acc1, 16, 64); acc1 += __shfl_xor(acc1, 32, 64);
        acc2 += __shfl_xor(acc2, 16, 64); acc2 += __shfl_xor(acc2, 32, 64);
        acc3 += __shfl_xor(acc3, 16, 64); acc3 += __shfl_xor(acc3, 32, 64);
        racc += __shfl_xor(racc, 16, 64); racc += __shfl_xor(racc, 32, 64);
#pragma unroll
        for (int o = 32; o; o >>= 1) s += __shfl_xor(s, o, 64);
        float inv = (end > base) ? 1.f / s : 0.f;
        if (g == 0) {
            float4 av = { acc0 * inv, acc1 * inv, acc2 * inv, acc3 * inv };
            *(float4*)&arow[w][lg << 2] = av;
            rrow[w][lg] = racc * inv;
        }
        // same-wave LDS stage: lane j picks feature j + e-term via WeWm
        float mm = arow[w][lane];
#pragma unroll
        for (int t = 0; t < 16; ++t) mm += rrow[w][t] * Ww[t * 64 + lane];
        size_t idx = (size_t)n * 64 + lane;
        float hv = lrelu(h_in[idx] + mm);
        h_out[idx] = hv;
        float x = hv * asj, y = hv * adj;
#pragma unroll
        for (int o = 32; o; o >>= 1) {
            x += __shfl_xor(x, o, 64);
            y += __shfl_xor(y, o, 64);
        }
        if (lane == 0) { hs_out[n] = x; hd_out[n] = y; }
    }
}

// block per graph readout (graph_id sorted -> contiguous ranges via binary search)
__global__ void k_readout(const float* __restrict__ h,
                          const float* __restrict__ d_edge,
                          const int* __restrict__ graph_id,
                          const float* __restrict__ i_node,
                          const float* __restrict__ W_i,
                          const float* __restrict__ w_d,
                          const float* __restrict__ b_d,
                          const float* __restrict__ W_mlp,
                          const float* __restrict__ b_mlp,
                          const float* __restrict__ W_out,
                          const float* __restrict__ b_out,
                          float* __restrict__ out) {
    int g = blockIdx.x, j = threadIdx.x;
    int lo = 0, hi = N_RN;
    while (lo < hi) { int mid = (lo + hi) >> 1; if (graph_id[mid] < g) lo = mid + 1; else hi = mid; }
    int start = lo;
    hi = N_RN;
    while (lo < hi) { int mid = (lo + hi) >> 1; if (graph_id[mid] < g + 1) lo = mid + 1; else hi = mid; }
    int end = lo;

    float wd = w_d[0], bd = b_d[0];
    float acc0 = 0.f, acc1 = 0.f, sg = 0.f;
    for (int n = start; n < end; ++n) {
        float hv = h[(size_t)n * 64 + j];
        float de = d_edge[n];
        float gate = 1.f / (1.f + __expf(-(de * wd + bd)));
        acc0 += hv;
        acc1 += gate * hv;
        sg += gate;
    }
    float hij = i_node[g] * W_i[j] + acc1;
    float pooled = acc0 + sg * hij;

    __shared__ float xa[64], xb[64];
    xa[j] = pooled;
    __syncthreads();
#pragma unroll
    for (int layer = 0; layer < 3; ++layer) {
        const float* W = W_mlp + layer * 4096;
        float* srcb = (layer & 1) ? xb : xa;
        float* dstb = (layer & 1) ? xa : xb;
        float acc = b_mlp[layer * 64 + j];
        for (int d = 0; d < 64; ++d) acc += srcb[d] * W[d * 64 + j];
        acc = fmaxf(acc, 0.f);
        __syncthreads();
        dstb[j] = acc;
        __syncthreads();
    }
    float v = xb[j] * W_out[j];
#pragma unroll
    for (int off = 32; off; off >>= 1) v += __shfl_xor(v, off, 64);
    if (j == 0) out[g] = v + b_out[0];
}

extern "C" void kernel_launch(void* const* d_in, const int* in_sizes, int n_in,
                              void* d_out, int out_size, void* d_ws, size_t ws_size,
                              hipStream_t stream) {
    const float* r_node  = (const float*)d_in[0];
    const float* i_node  = (const float*)d_in[1];
    const float* r_edge  = (const float*)d_in[2];
    const float* d_edge  = (const float*)d_in[3];
    const int*   r2r_src = (const int*)d_in[4];
    const int*   r2r_dst = (const int*)d_in[5];
    const int*   graph_id= (const int*)d_in[6];
    const float* W_r     = (const float*)d_in[7];
    const float* W_i     = (const float*)d_in[8];
    const float* W_e     = (const float*)d_in[9];
    const float* Wm      = (const float*)d_in[10];
    const float* a_s     = (const float*)d_in[11];
    const float* a_d     = (const float*)d_in[12];
    const float* a_e     = (const float*)d_in[13];
    const float* w_d     = (const float*)d_in[14];
    const float* b_d     = (const float*)d_in[15];
    const float* W_mlp   = (const float*)d_in[16];
    const float* b_mlp   = (const float*)d_in[17];
    const float* W_out   = (const float*)d_in[18];
    const float* b_out   = (const float*)d_in[19];
    float* out = (float*)d_out;

    float* ws = (float*)d_ws;
    float* h0   = ws;                                  // N*64
    float* h1   = h0 + (size_t)N_RN * 64;              // N*64
    float* hwm  = h1 + (size_t)N_RN * 64;              // N*64
    float* hs0  = hwm + (size_t)N_RN * 64;             // N
    float* hd0  = hs0 + N_RN;                          // N
    float* hs1  = hd0 + N_RN;                          // N
    float* hd1  = hs1 + N_RN;                          // N
    float* WeWm = hd1 + N_RN;                          // 4*16*64
    float* wasb = WeWm + 4096;                         // 4*16
    int*   deg  = (int*)(wasb + 64);                   // N
    int*   offs = deg + N_RN;                          // N+1
    int*   cur  = offs + N_RN + 1;                     // N
    int*   bsum = cur + N_RN;                          // 512
    int*   src_perm = bsum + 512;                      // E
    float* r16_perm = (float*)(src_perm + N_ED);       // 16*E

    k_embed_h<<<2048, 256, 0, stream>>>(r_node, W_r, a_s, a_d, h0, hs0, hd0);
    k_wewm<<<17, 256, 0, stream>>>(W_e, Wm, a_e, WeWm, wasb);

    hipMemsetAsync(deg, 0, N_RN * sizeof(int), stream);
    k_hist<<<(N_ED + 255) / 256, 256, 0, stream>>>(r2r_dst, deg);
    k_scan_a<<<SCAN_NB, SCAN_CH, 0, stream>>>(deg, bsum);
    k_scan_b<<<1, 512, 0, stream>>>(bsum);
    k_scan_c<<<SCAN_NB, SCAN_CH, 0, stream>>>(deg, bsum, offs, cur);
    k_scatter<<<(N_ED + 255) / 256, 256, 0, stream>>>(r_edge, r2r_src, r2r_dst,
                                                      cur, src_perm, r16_perm);

    float* hin = h0;  float* hout = h1;
    float* hsi = hs0; float* hdi = hd0;
    float* hso = hs1; float* hdo = hd1;
    for (int l = 0; l < 4; ++l) {
        int ln = (l + 1) & 3;
        k_hwm<<<2048, 256, 0, stream>>>(hin, Wm + l * 4096, hwm);
        k_layer<<<2048, 256, 0, stream>>>(hin, hwm, hsi, hdi, offs, src_perm, r16_perm,
                                          wasb + l * 16, WeWm + l * 1024,
                                          a_s + ln * 64, a_d + ln * 64,
                                          hout, hso, hdo);
        float* t;
        t = hin; hin = hout; hout = t;
        t = hsi; hsi = hso; hso = t;
        t = hdi; hdi = hdo; hdo = t;
    }

    k_readout<<<N_G, 64, 0, stream>>>(hin, d_edge, graph_id, i_node, W_i, w_d, b_d,
                                      W_mlp, b_mlp, W_out, b_out, out);
}

// Round 3
// 729.638 us; speedup vs baseline: 1.2666x; 1.2666x over previous
//
#include <hip/hip_runtime.h>
#include <math.h>

#define N_RN 100000
#define N_ED 1200000
#define N_G  4096
#define SCAN_CH 256
#define SCAN_NB ((N_RN + SCAN_CH - 1) / SCAN_CH)   // 391

__device__ __forceinline__ float lrelu(float x) { return x > 0.f ? x : 0.1f * x; }

// h = r_node @ W_r (wave/node, lane=col, row via coalesced LDS); fused hs/hd layer0
__global__ void k_embed_h(const float* __restrict__ r_node,
                          const float* __restrict__ W_r,
                          const float* __restrict__ a_s0,
                          const float* __restrict__ a_d0,
                          float* __restrict__ h,
                          float* __restrict__ hs, float* __restrict__ hd) {
    __shared__ float Wl[64 * 64];
    __shared__ float arow[4][64];
    int tid = threadIdx.x;
    for (int i = tid; i < 4096; i += 256) Wl[i] = W_r[i];
    __syncthreads();
    int lane = tid & 63, w = tid >> 6;
    float asj = a_s0[lane], adj = a_d0[lane];
    int wid = blockIdx.x * 4 + w;
    int nw = gridDim.x * 4;
    for (int n = wid; n < N_RN; n += nw) {
        arow[w][lane] = r_node[(size_t)n * 64 + lane];
        float acc = 0.f;
#pragma unroll
        for (int d4 = 0; d4 < 16; ++d4) {
            float4 a = *(const float4*)&arow[w][d4 * 4];
            int d = d4 * 4;
            acc += a.x * Wl[(d + 0) * 64 + lane];
            acc += a.y * Wl[(d + 1) * 64 + lane];
            acc += a.z * Wl[(d + 2) * 64 + lane];
            acc += a.w * Wl[(d + 3) * 64 + lane];
        }
        h[(size_t)n * 64 + lane] = acc;
        float x = acc * asj, y = acc * adj;
#pragma unroll
        for (int off = 32; off; off >>= 1) {
            x += __shfl_xor(x, off, 64);
            y += __shfl_xor(y, off, 64);
        }
        if (lane == 0) { hs[n] = x; hd[n] = y; }
    }
}

// WeWm[l] = W_e @ Wm[l]  (16x64 per layer); also was_all[l][t] = W_e[t,:] . a_e[l]
__global__ void k_wewm(const float* __restrict__ W_e,
                       const float* __restrict__ Wm,
                       const float* __restrict__ a_e,
                       float* __restrict__ WeWm,
                       float* __restrict__ was_all) {
    int idx = blockIdx.x * blockDim.x + threadIdx.x;   // 17*256
    if (idx < 4096) {
        int l = idx >> 10, rem = idx & 1023;
        int t = rem >> 6, j = rem & 63;
        float acc = 0.f;
        for (int d = 0; d < 64; ++d)
            acc += W_e[t * 64 + d] * Wm[l * 4096 + d * 64 + j];
        WeWm[idx] = acc;
    } else {
        int r = idx - 4096;
        if (r < 64) {
            int l = r >> 4, t = r & 15;
            float acc = 0.f;
            for (int j = 0; j < 64; ++j)
                acc += W_e[t * 64 + j] * a_e[l * 64 + j];
            was_all[r] = acc;
        }
    }
}

// ---- CSR build ----
__global__ void k_hist(const int* __restrict__ dst, int* __restrict__ deg) {
    int k = blockIdx.x * blockDim.x + threadIdx.x;
    if (k < N_ED) atomicAdd(deg + dst[k], 1);
}

__global__ void k_scan_a(const int* __restrict__ deg, int* __restrict__ bsum) {
    __shared__ int lds[SCAN_CH];
    int b = blockIdx.x, t = threadIdx.x;
    int i = b * SCAN_CH + t;
    int v = (i < N_RN) ? deg[i] : 0;
    lds[t] = v;
    __syncthreads();
    for (int d = 128; d; d >>= 1) {
        if (t < d) lds[t] += lds[t + d];
        __syncthreads();
    }
    if (t == 0) bsum[b] = lds[0];
}

__global__ void k_scan_b(int* __restrict__ bsum) {
    __shared__ int lds[512];
    int t = threadIdx.x;
    int v = (t < SCAN_NB) ? bsum[t] : 0;
    lds[t] = v;
    __syncthreads();
    for (int d = 1; d < 512; d <<= 1) {
        int u = (t >= d) ? lds[t - d] : 0;
        __syncthreads();
        lds[t] += u;
        __syncthreads();
    }
    if (t < SCAN_NB) bsum[t] = lds[t] - v;  // exclusive
}

__global__ void k_scan_c(const int* __restrict__ deg, const int* __restrict__ bsum,
                         int* __restrict__ off, int* __restrict__ cur) {
    __shared__ int lds[SCAN_CH];
    int b = blockIdx.x, t = threadIdx.x;
    int i = b * SCAN_CH + t;
    int v = (i < N_RN) ? deg[i] : 0;
    lds[t] = v;
    __syncthreads();
    for (int d = 1; d < SCAN_CH; d <<= 1) {
        int u = (t >= d) ? lds[t - d] : 0;
        __syncthreads();
        lds[t] += u;
        __syncthreads();
    }
    if (i < N_RN) {
        int incl = bsum[b] + lds[t];
        off[i + 1] = incl;
        cur[i] = incl - v;
        if (i == 0) off[0] = 0;
    }
}

// scatter edges into dst-sorted order: src_perm + raw 16-float edge row (r16_perm)
__global__ void k_scatter(const float* __restrict__ r_edge,
                          const int* __restrict__ src, const int* __restrict__ dst,
                          int* __restrict__ cur,
                          int* __restrict__ src_perm,
                          float* __restrict__ r16_perm) {
    int k = blockIdx.x * blockDim.x + threadIdx.x;
    if (k >= N_ED) return;
    const float4* row = (const float4*)(r_edge + (size_t)k * 16);
    float4 r0 = row[0], r1 = row[1], r2 = row[2], r3 = row[3];
    int pos = atomicAdd(cur + dst[k], 1);
    src_perm[pos] = src[k];
    float4* o = (float4*)(r16_perm + (size_t)pos * 16);
    o[0] = r0; o[1] = r1; o[2] = r2; o[3] = r3;
}

// fused per-layer conv: 4 nodes per wave (16-lane group per node).
// Lane lg owns output dims 4lg..4lg+3 -> acc/racc reductions are lane-local.
// Phase 1: lane-per-edge logits, in-register edge dot. Phase 2: weights
// broadcast via shfl(width 16), gather h rows, unrolled x2.
// Epilogue: group-level 64x64 matvec from LDS-staged agg row (Wm fused back).
__global__ void k_layer(const float* __restrict__ h_in,
                        const float* __restrict__ hs, const float* __restrict__ hd,
                        const int* __restrict__ off,
                        const int* __restrict__ src_perm,
                        const float* __restrict__ r16_perm,
                        const float* __restrict__ was_l,   // 16 floats: W_e @ a_e[l]
                        const float* __restrict__ Wm_l,
                        const float* __restrict__ WeWm_l,
                        const float* __restrict__ a_s_n, const float* __restrict__ a_d_n,
                        float* __restrict__ h_out,
                        float* __restrict__ hs_out, float* __restrict__ hd_out) {
    __shared__ float Wl[4096];
    __shared__ float Ww[1024];
    __shared__ float arow[8][4 * 68 + 4];   // 68-pad: groups land on distinct banks
    int tid = threadIdx.x;
    for (int i = tid; i < 4096; i += 512) Wl[i] = Wm_l[i];
    for (int i = tid; i < 1024; i += 512) Ww[i] = WeWm_l[i];
    __syncthreads();
    int lane = tid & 63, w = tid >> 6;
    int g = lane >> 4, lg = lane & 15;
    float wr[16];
#pragma unroll
    for (int t = 0; t < 16; ++t) wr[t] = was_l[t];
    float4 as4 = *(const float4*)&a_s_n[lg << 2];
    float4 ad4 = *(const float4*)&a_d_n[lg << 2];
    int Wv = blockIdx.x * 8 + w;
    int NW = gridDim.x * 8;
    for (int nb = Wv * 4; nb < N_RN; nb += NW * 4) {
        int n = nb + g;
        bool nact = n < N_RN;
        int base = 0, end = 0;
        if (nact) { base = off[n]; end = off[n + 1]; }
        float hdn = nact ? hd[n] : 0.f;
        float m = -1e38f, s = 0.f, racc = 0.f;
        float ax = 0.f, ay = 0.f, az = 0.f, aw = 0.f;
        int nch = (end - base + 15) >> 4;
        int nmax = nch;
        nmax = max(nmax, __shfl_xor(nmax, 16, 64));
        nmax = max(nmax, __shfl_xor(nmax, 32, 64));
        for (int c = 0; c < nmax; ++c) {
            int cb = base + (c << 4);
            int rem = end - cb;
            int cnt = rem > 16 ? 16 : (rem > 0 ? rem : 0);
            float lgt = -1e38f;
            float wvv = 0.f;
            int sk = 0;
            bool act = lg < cnt;
            if (act) {
                int pos = cb + lg;
                sk = src_perm[pos];
                const float4* rp = (const float4*)(r16_perm + (size_t)pos * 16);
                float4 r0 = rp[0], r1 = rp[1], r2 = rp[2], r3 = rp[3];
                float ep = r0.x * wr[0] + r0.y * wr[1] + r0.z * wr[2] + r0.w * wr[3]
                         + r1.x * wr[4] + r1.y * wr[5] + r1.z * wr[6] + r1.w * wr[7]
                         + r2.x * wr[8] + r2.y * wr[9] + r2.z * wr[10] + r2.w * wr[11]
                         + r3.x * wr[12] + r3.y * wr[13] + r3.z * wr[14] + r3.w * wr[15];
                lgt = lrelu(hs[sk] + hdn + ep);
            }
            float cm = lgt;
            cm = fmaxf(cm, __shfl_xor(cm, 1, 16));
            cm = fmaxf(cm, __shfl_xor(cm, 2, 16));
            cm = fmaxf(cm, __shfl_xor(cm, 4, 16));
            cm = fmaxf(cm, __shfl_xor(cm, 8, 16));
            float newm = fmaxf(m, cm);
            float scale = (m > -1e37f) ? __expf(m - newm) : 0.f;
            s *= scale; racc *= scale;
            ax *= scale; ay *= scale; az *= scale; aw *= scale;
            m = newm;
            if (act) wvv = __expf(lgt - m);
            s += wvv;
            // phase 2: unrolled x2; lane lg accumulates dims 4lg..4lg+3
            int e = 0;
            for (; e + 1 < cnt; e += 2) {
                float wgt0 = __shfl(wvv, e, 16);
                int   sk0  = __shfl(sk, e, 16);
                float wgt1 = __shfl(wvv, e + 1, 16);
                int   sk1  = __shfl(sk, e + 1, 16);
                const float4 h0v = *(const float4*)(h_in + (size_t)sk0 * 64 + (lg << 2));
                const float4 h1v = *(const float4*)(h_in + (size_t)sk1 * 64 + (lg << 2));
                float q0 = r16_perm[(size_t)(cb + e) * 16 + lg];
                float q1 = r16_perm[(size_t)(cb + e + 1) * 16 + lg];
                ax += wgt0 * h0v.x + wgt1 * h1v.x;
                ay += wgt0 * h0v.y + wgt1 * h1v.y;
                az += wgt0 * h0v.z + wgt1 * h1v.z;
                aw += wgt0 * h0v.w + wgt1 * h1v.w;
                racc += wgt0 * q0 + wgt1 * q1;
            }
            if (e < cnt) {
                float wgt0 = __shfl(wvv, e, 16);
                int   sk0  = __shfl(sk, e, 16);
                const float4 h0v = *(const float4*)(h_in + (size_t)sk0 * 64 + (lg << 2));
                float q0 = r16_perm[(size_t)(cb + e) * 16 + lg];
                ax += wgt0 * h0v.x; ay += wgt0 * h0v.y;
                az += wgt0 * h0v.z; aw += wgt0 * h0v.w;
                racc += wgt0 * q0;
            }
        }
        // softmax denominator (group sum)
        s += __shfl_xor(s, 1, 16);
        s += __shfl_xor(s, 2, 16);
        s += __shfl_xor(s, 4, 16);
        s += __shfl_xor(s, 8, 16);
        float inv = (end > base) ? 1.f / s : 0.f;
        // stage normalized agg row for the group matvec
        float* ar = &arow[w][g * 68];
        *(float4*)&ar[lg << 2] = make_float4(ax * inv, ay * inv, az * inv, aw * inv);
        float mx = 0.f, my = 0.f, mz = 0.f, mw = 0.f;
#pragma unroll
        for (int d4 = 0; d4 < 16; ++d4) {
            float4 a = *(const float4*)&ar[d4 << 2];      // LDS broadcast within group
            const float* wl = &Wl[(d4 << 2) * 64 + (lg << 2)];
            float4 w0 = *(const float4*)&wl[0];
            float4 w1 = *(const float4*)&wl[64];
            float4 w2 = *(const float4*)&wl[128];
            float4 w3 = *(const float4*)&wl[192];
            mx += a.x * w0.x + a.y * w1.x + a.z * w2.x + a.w * w3.x;
            my += a.x * w0.y + a.y * w1.y + a.z * w2.y + a.w * w3.y;
            mz += a.x * w0.z + a.y * w1.z + a.z * w2.z + a.w * w3.z;
            mw += a.x * w0.w + a.y * w1.w + a.z * w2.w + a.w * w3.w;
        }
        float rs = racc * inv;
#pragma unroll
        for (int t = 0; t < 16; ++t) {
            float rt = __shfl(rs, t, 16);
            const float4 wt = *(const float4*)&Ww[t * 64 + (lg << 2)];
            mx += rt * wt.x; my += rt * wt.y; mz += rt * wt.z; mw += rt * wt.w;
        }
        if (nact) {
            const float4 hi4 = *(const float4*)(h_in + (size_t)n * 64 + (lg << 2));
            float4 hv;
            hv.x = lrelu(hi4.x + mx); hv.y = lrelu(hi4.y + my);
            hv.z = lrelu(hi4.z + mz); hv.w = lrelu(hi4.w + mw);
            *(float4*)(h_out + (size_t)n * 64 + (lg << 2)) = hv;
            float x = hv.x * as4.x + hv.y * as4.y + hv.z * as4.z + hv.w * as4.w;
            float y = hv.x * ad4.x + hv.y * ad4.y + hv.z * ad4.z + hv.w * ad4.w;
            x += __shfl_xor(x, 1, 16); x += __shfl_xor(x, 2, 16);
            x += __shfl_xor(x, 4, 16); x += __shfl_xor(x, 8, 16);
            y += __shfl_xor(y, 1, 16); y += __shfl_xor(y, 2, 16);
            y += __shfl_xor(y, 4, 16); y += __shfl_xor(y, 8, 16);
            if (lg == 0) { hs_out[n] = x; hd_out[n] = y; }
        }
    }
}

// block per graph readout (graph_id sorted -> contiguous ranges via binary search)
__global__ void k_readout(const float* __restrict__ h,
                          const float* __restrict__ d_edge,
                          const int* __restrict__ graph_id,
                          const float* __restrict__ i_node,
                          const float* __restrict__ W_i,
                          const float* __restrict__ w_d,
                          const float* __restrict__ b_d,
                          const float* __restrict__ W_mlp,
                          const float* __restrict__ b_mlp,
                          const float* __restrict__ W_out,
                          const float* __restrict__ b_out,
                          float* __restrict__ out) {
    int g = blockIdx.x, j = threadIdx.x;
    int lo = 0, hi = N_RN;
    while (lo < hi) { int mid = (lo + hi) >> 1; if (graph_id[mid] < g) lo = mid + 1; else hi = mid; }
    int start = lo;
    hi = N_RN;
    while (lo < hi) { int mid = (lo + hi) >> 1; if (graph_id[mid] < g + 1) lo = mid + 1; else hi = mid; }
    int end = lo;

    float wd = w_d[0], bd = b_d[0];
    float acc0 = 0.f, acc1 = 0.f, sg = 0.f;
    for (int n = start; n < end; ++n) {
        float hv = h[(size_t)n * 64 + j];
        float de = d_edge[n];
        float gate = 1.f / (1.f + __expf(-(de * wd + bd)));
        acc0 += hv;
        acc1 += gate * hv;
        sg += gate;
    }
    float hij = i_node[g] * W_i[j] + acc1;
    float pooled = acc0 + sg * hij;

    __shared__ float xa[64], xb[64];
    xa[j] = pooled;
    __syncthreads();
#pragma unroll
    for (int layer = 0; layer < 3; ++layer) {
        const float* W = W_mlp + layer * 4096;
        float* srcb = (layer & 1) ? xb : xa;
        float* dstb = (layer & 1) ? xa : xb;
        float acc = b_mlp[layer * 64 + j];
        for (int d = 0; d < 64; ++d) acc += srcb[d] * W[d * 64 + j];
        acc = fmaxf(acc, 0.f);
        __syncthreads();
        dstb[j] = acc;
        __syncthreads();
    }
    float v = xb[j] * W_out[j];
#pragma unroll
    for (int off = 32; off; off >>= 1) v += __shfl_xor(v, off, 64);
    if (j == 0) out[g] = v + b_out[0];
}

extern "C" void kernel_launch(void* const* d_in, const int* in_sizes, int n_in,
                              void* d_out, int out_size, void* d_ws, size_t ws_size,
                              hipStream_t stream) {
    const float* r_node  = (const float*)d_in[0];
    const float* i_node  = (const float*)d_in[1];
    const float* r_edge  = (const float*)d_in[2];
    const float* d_edge  = (const float*)d_in[3];
    const int*   r2r_src = (const int*)d_in[4];
    const int*   r2r_dst = (const int*)d_in[5];
    const int*   graph_id= (const int*)d_in[6];
    const float* W_r     = (const float*)d_in[7];
    const float* W_i     = (const float*)d_in[8];
    const float* W_e     = (const float*)d_in[9];
    const float* Wm      = (const float*)d_in[10];
    const float* a_s     = (const float*)d_in[11];
    const float* a_d     = (const float*)d_in[12];
    const float* a_e     = (const float*)d_in[13];
    const float* w_d     = (const float*)d_in[14];
    const float* b_d     = (const float*)d_in[15];
    const float* W_mlp   = (const float*)d_in[16];
    const float* b_mlp   = (const float*)d_in[17];
    const float* W_out   = (const float*)d_in[18];
    const float* b_out   = (const float*)d_in[19];
    float* out = (float*)d_out;

    float* ws = (float*)d_ws;
    float* h0   = ws;                                  // N*64
    float* h1   = h0 + (size_t)N_RN * 64;              // N*64
    float* hs0  = h1 + (size_t)N_RN * 64;              // N
    float* hd0  = hs0 + N_RN;                          // N
    float* hs1  = hd0 + N_RN;                          // N
    float* hd1  = hs1 + N_RN;                          // N
    float* WeWm = hd1 + N_RN;                          // 4*16*64
    float* wasb = WeWm + 4096;                         // 4*16
    int*   deg  = (int*)(wasb + 64);                   // N
    int*   offs = deg + N_RN;                          // N+1
    int*   cur  = offs + N_RN + 1;                     // N
    int*   bsum = cur + N_RN;                          // 512
    int*   src_perm = bsum + 512;                      // E
    float* r16_perm = (float*)(src_perm + N_ED);       // 16*E

    k_embed_h<<<2048, 256, 0, stream>>>(r_node, W_r, a_s, a_d, h0, hs0, hd0);
    k_wewm<<<17, 256, 0, stream>>>(W_e, Wm, a_e, WeWm, wasb);

    hipMemsetAsync(deg, 0, N_RN * sizeof(int), stream);
    k_hist<<<(N_ED + 255) / 256, 256, 0, stream>>>(r2r_dst, deg);
    k_scan_a<<<SCAN_NB, SCAN_CH, 0, stream>>>(deg, bsum);
    k_scan_b<<<1, 512, 0, stream>>>(bsum);
    k_scan_c<<<SCAN_NB, SCAN_CH, 0, stream>>>(deg, bsum, offs, cur);
    k_scatter<<<(N_ED + 255) / 256, 256, 0, stream>>>(r_edge, r2r_src, r2r_dst,
                                                      cur, src_perm, r16_perm);

    float* hin = h0;  float* hout = h1;
    float* hsi = hs0; float* hdi = hd0;
    float* hso = hs1; float* hdo = hd1;
    for (int l = 0; l < 4; ++l) {
        int ln = (l + 1) & 3;
        k_layer<<<1024, 512, 0, stream>>>(hin, hsi, hdi, offs, src_perm, r16_perm,
                                          wasb + l * 16, Wm + l * 4096, WeWm + l * 1024,
                                          a_s + ln * 64, a_d + ln * 64,
                                          hout, hso, hdo);
        float* t;
        t = hin; hin = hout; hout = t;
        t = hsi; hsi = hso; hso = t;
        t = hdi; hdi = hdo; hdo = t;
    }

    k_readout<<<N_G, 64, 0, stream>>>(hin, d_edge, graph_id, i_node, W_i, w_d, b_d,
                                      W_mlp, b_mlp, W_out, b_out, out);
}